// Round 1
// baseline (662.293 us; speedup 1.0000x reference)
//
#include <hip/hip_runtime.h>

#define CC   128
#define HH_  64
#define WW_  64
#define BB   8
#define HWSZ (HH_*WW_)      // 4096
#define CHW  (CC*HWSZ)      // 524288
#define BCHW (BB*CHW)       // 4194304
#define PAD  3
#define NP   49

// ---------------- Kernel 1: q/k/v = W*x + b (1x1 conv) ----------------
// One block per (b,h) row. x row staged in LDS (128 ch x 64 px = 32 KB).
// Thread tile: 4 outputs x 4 pixels -> 16 FMA per ds_read_b128.
__global__ __launch_bounds__(256) void qkv_proj(
    const float* __restrict__ x,
    const float* __restrict__ Wq, const float* __restrict__ bq,
    const float* __restrict__ Wk, const float* __restrict__ bk,
    const float* __restrict__ Wv, const float* __restrict__ bv,
    float* __restrict__ qkv)   // [3][B][C][H][W]
{
    __shared__ float xs[CC][WW_];   // 32 KB
    const int b   = blockIdx.x / HH_;
    const int h   = blockIdx.x % HH_;
    const int tid = threadIdx.x;

    const float* xrow = x + (size_t)b*CHW + h*WW_;
    for (int i = tid; i < CC*WW_; i += 256) {
        int c = i >> 6, w = i & 63;
        xs[c][w] = xrow[c*HWSZ + w];
    }
    __syncthreads();

    const int wq = (tid & 15) << 2;   // pixel quad
    const int oq = tid >> 4;          // output quad (0..15)

    for (int pass = 0; pass < 6; ++pass) {
        const int o4   = pass*64 + oq*4;      // 0..380, proj-uniform per pass
        const int proj = o4 >> 7;
        const int o    = o4 & 127;
        const float* Wp = (proj == 0) ? Wq : (proj == 1 ? Wk : Wv);
        const float* Bp = (proj == 0) ? bq : (proj == 1 ? bk : bv);

        float acc[4][4];
        #pragma unroll
        for (int j = 0; j < 4; ++j) {
            float bj = Bp[o + j];
            #pragma unroll
            for (int i2 = 0; i2 < 4; ++i2) acc[j][i2] = bj;
        }

        #pragma unroll 4
        for (int c = 0; c < CC; ++c) {
            float4 xv = *(const float4*)&xs[c][wq];
            #pragma unroll
            for (int j = 0; j < 4; ++j) {
                float wt = Wp[(o + j)*CC + c];
                acc[j][0] = fmaf(wt, xv.x, acc[j][0]);
                acc[j][1] = fmaf(wt, xv.y, acc[j][1]);
                acc[j][2] = fmaf(wt, xv.z, acc[j][2]);
                acc[j][3] = fmaf(wt, xv.w, acc[j][3]);
            }
        }

        float* outp = qkv + (size_t)proj*BCHW + (size_t)b*CHW + h*WW_ + wq;
        #pragma unroll
        for (int j = 0; j < 4; ++j) {
            float4 st = make_float4(acc[j][0], acc[j][1], acc[j][2], acc[j][3]);
            *(float4*)&outp[(o + j)*HWSZ] = st;
        }
    }
}

// ---------------- Kernel 2: local attention ----------------
// One block per (b,h) row; 4 waves, each a 32-channel slice; lane = pixel w.
// Phase A: per-wave partial logits (49 regs) -> LDS.
// Phase B: wave 0 reduces 4 slices, max-subtracted softmax -> LDS.
// Phase C: y = attn . v with attn hoisted into 49 regs.
__global__ __launch_bounds__(256) void locatt(
    const float* __restrict__ qkv, float* __restrict__ out)
{
    __shared__ float lg[4][NP][WW_];   // 50176 B
    __shared__ float dn[WW_];
    const int b   = blockIdx.x / HH_;
    const int h   = blockIdx.x % HH_;
    const int tid = threadIdx.x;
    const int s   = tid >> 6;   // wave / channel-slice
    const int w   = tid & 63;   // pixel

    const float* qp = qkv;
    const float* kp = qkv + BCHW;
    const float* vp = qkv + (size_t)2*BCHW;
    const size_t base = (size_t)b*CHW + h*WW_;

    float acc[NP];
    #pragma unroll
    for (int p = 0; p < NP; ++p) acc[p] = 0.f;

    for (int ci = 0; ci < 32; ++ci) {
        const int c = s*32 + ci;
        const float* krow = kp + (size_t)b*CHW + (size_t)c*HWSZ;
        const float qv = qp[base + (size_t)c*HWSZ + w];
        #pragma unroll
        for (int p = 0; p < NP; ++p) {
            const int hh = h + p/7 - PAD;      // block-uniform predicate
            if ((unsigned)hh < HH_) {
                const int ww = w + p%7 - PAD;  // per-lane edge predicate
                float kv = ((unsigned)ww < WW_) ? krow[hh*WW_ + ww] : 0.f;
                acc[p] = fmaf(qv, kv, acc[p]);
            }
        }
    }
    #pragma unroll
    for (int p = 0; p < NP; ++p) lg[s][p][w] = acc[p];
    __syncthreads();

    if (tid < 64) {   // wave 0: reduce + softmax (OOB logits are exactly 0)
        float tv[NP];
        float m = -1e30f;
        #pragma unroll
        for (int p = 0; p < NP; ++p) {
            float t = lg[0][p][w] + lg[1][p][w] + lg[2][p][w] + lg[3][p][w];
            tv[p] = t;
            m = fmaxf(m, t);
        }
        float d = 0.f;
        #pragma unroll
        for (int p = 0; p < NP; ++p) {
            float e = __expf(tv[p] - m);
            d += e;
            lg[0][p][w] = e;
        }
        dn[w] = 1.f / d;
    }
    __syncthreads();

    float a[NP];
    #pragma unroll
    for (int p = 0; p < NP; ++p) a[p] = lg[0][p][w];
    const float scale = dn[w];

    for (int ci = 0; ci < 32; ++ci) {
        const int c = s*32 + ci;
        const float* vrow = vp + (size_t)b*CHW + (size_t)c*HWSZ;
        float acc2 = 0.f;
        #pragma unroll
        for (int p = 0; p < NP; ++p) {
            const int hh = h + p/7 - PAD;
            if ((unsigned)hh < HH_) {
                const int ww = w + p%7 - PAD;
                float vv = ((unsigned)ww < WW_) ? vrow[hh*WW_ + ww] : 0.f;
                acc2 = fmaf(a[p], vv, acc2);
            }
        }
        out[base + (size_t)c*HWSZ + w] = acc2 * scale;
    }
}

extern "C" void kernel_launch(void* const* d_in, const int* in_sizes, int n_in,
                              void* d_out, int out_size, void* d_ws, size_t ws_size,
                              hipStream_t stream) {
    const float* x  = (const float*)d_in[0];
    const float* Wq = (const float*)d_in[1];
    const float* bq = (const float*)d_in[2];
    const float* Wk = (const float*)d_in[3];
    const float* bk = (const float*)d_in[4];
    const float* Wv = (const float*)d_in[5];
    const float* bv = (const float*)d_in[6];
    float* out = (float*)d_out;
    float* qkv = (float*)d_ws;   // needs 3*BCHW*4 = 50.3 MB scratch

    qkv_proj<<<BB*HH_, 256, 0, stream>>>(x, Wq, bq, Wk, bk, Wv, bv, qkv);
    locatt  <<<BB*HH_, 256, 0, stream>>>(qkv, out);
}

// Round 2
// 162.299 us; speedup vs baseline: 4.0807x; 4.0807x over previous
//
#include <hip/hip_runtime.h>

#define CC   128
#define HH_  64
#define WW_  64
#define BB   8
#define HWSZ (HH_*WW_)      // 4096
#define CHW  (CC*HWSZ)      // 524288
#define BCHW (BB*CHW)       // 4194304
#define PAD  3
#define NP   49

// ================= Kernel 1: q/k/v = W*x + b as register-tiled GEMM =========
// Grid (256 px-tiles, 6 out-groups). Block 128 thr. Per block: 64 outs x 128 px.
// Thread tile 8 outs x 8 px (two float4 quads 64 apart -> 2-way LDS alias, free).
__global__ __launch_bounds__(128) void qkv_proj(
    const float* __restrict__ x,
    const float* __restrict__ Wq, const float* __restrict__ bq,
    const float* __restrict__ Wk, const float* __restrict__ bk,
    const float* __restrict__ Wv, const float* __restrict__ bv,
    float* __restrict__ qkv)   // [3][B][C][H][W]
{
    __shared__ float xs[32][132];   // 16.5 KB, padded
    __shared__ float ws[32][68];    // 8.5 KB, padded (68: keeps float4 align)
    const int pt  = blockIdx.x;            // 0..255
    const int og  = blockIdx.y;            // 0..5
    const int b   = pt >> 5;
    const int hw0 = (pt & 31) << 7;
    const int tid = threadIdx.x;

    const int proj = og >> 1;
    const int row0 = (og & 1) << 6;
    const float* Wp = (proj == 0) ? Wq : (proj == 1 ? Wk : Wv);
    const float* Bp = (proj == 0) ? bq : (proj == 1 ? bk : bv);

    const int o8  = (tid >> 4) << 3;   // 0..56 (local out)
    const int px4 = (tid & 15) << 2;   // 0..60 (px quad; second quad at +64)

    float acc[8][8];
    #pragma unroll
    for (int j = 0; j < 8; ++j) {
        float bj = Bp[row0 + o8 + j];
        #pragma unroll
        for (int i = 0; i < 8; ++i) acc[j][i] = bj;
    }

    const float* xb = x + (size_t)b*CHW + hw0;

    for (int ck = 0; ck < 4; ++ck) {
        const int c0 = ck << 5;
        __syncthreads();
        // stage x: 32 ch x 128 px = 1024 float4, 8 per thread
        #pragma unroll
        for (int i = 0; i < 8; ++i) {
            int f  = tid + (i << 7);
            int c  = f >> 5, q4 = (f & 31) << 2;
            *(float4*)&xs[c][q4] = *(const float4*)&xb[(size_t)(c0 + c)*HWSZ + q4];
        }
        // stage W (transposed): 64 outs x 32 ch = 512 float4, 4 per thread
        #pragma unroll
        for (int i = 0; i < 4; ++i) {
            int f = tid + (i << 7);
            int o = f >> 3, c4 = (f & 7) << 2;
            float4 wv = *(const float4*)&Wp[(size_t)(row0 + o)*CC + c0 + c4];
            ws[c4+0][o] = wv.x; ws[c4+1][o] = wv.y;
            ws[c4+2][o] = wv.z; ws[c4+3][o] = wv.w;
        }
        __syncthreads();

        #pragma unroll 8
        for (int c = 0; c < 32; ++c) {
            float4 w0 = *(const float4*)&ws[c][o8];
            float4 w1 = *(const float4*)&ws[c][o8 + 4];
            float4 x0 = *(const float4*)&xs[c][px4];
            float4 x1 = *(const float4*)&xs[c][px4 + 64];
            float wr[8] = {w0.x,w0.y,w0.z,w0.w,w1.x,w1.y,w1.z,w1.w};
            float xr[8] = {x0.x,x0.y,x0.z,x0.w,x1.x,x1.y,x1.z,x1.w};
            #pragma unroll
            for (int j = 0; j < 8; ++j)
                #pragma unroll
                for (int i = 0; i < 8; ++i)
                    acc[j][i] = fmaf(wr[j], xr[i], acc[j][i]);
        }
    }

    float* op = qkv + (size_t)proj*BCHW + (size_t)b*CHW + hw0;
    #pragma unroll
    for (int j = 0; j < 8; ++j) {
        const int row = row0 + o8 + j;
        float4 s0 = make_float4(acc[j][0], acc[j][1], acc[j][2], acc[j][3]);
        float4 s1 = make_float4(acc[j][4], acc[j][5], acc[j][6], acc[j][7]);
        *(float4*)&op[(size_t)row*HWSZ + px4]      = s0;
        *(float4*)&op[(size_t)row*HWSZ + px4 + 64] = s1;
    }
}

// ================= Kernel 2: local attention with LDS-staged k/v ============
// Block per (b,h), 256 thr (4 waves), lane = pixel w.
// k/v streamed in 16-channel chunks through ks[16][7][72] (halo cols zeroed
// once). Phase A: 49 positions split across waves (12/12/12/13), no reduce.
// Phase C: channels split across waves, 49 attn weights in registers.
__device__ __forceinline__ void load_chunk(const float* __restrict__ src,
                                           int h, int c0, float4* stg) {
    const int tid = threadIdx.x;
    #pragma unroll
    for (int i = 0; i < 7; ++i) {
        int f   = tid + (i << 8);          // 0..1791 = 16ch * 7r * 16quads
        int c   = f / 112;
        int rem = f - c*112;
        int r   = rem >> 4;
        int q4  = (rem & 15) << 2;
        int hh  = h + r - PAD;
        if ((unsigned)hh < (unsigned)HH_)
            stg[i] = *(const float4*)&src[(size_t)(c0 + c)*HWSZ + hh*WW_ + q4];
        else
            stg[i] = make_float4(0.f, 0.f, 0.f, 0.f);
    }
}

__device__ __forceinline__ void store_chunk(float (*ks)[7][72], const float4* stg) {
    const int tid = threadIdx.x;
    #pragma unroll
    for (int i = 0; i < 7; ++i) {
        int f   = tid + (i << 8);
        int c   = f / 112;
        int rem = f - c*112;
        int r   = rem >> 4;
        int q4  = (rem & 15) << 2;
        *(float4*)&ks[c][r][4 + q4] = stg[i];
    }
}

__global__ __launch_bounds__(256) void locatt(
    const float* __restrict__ qkv, float* __restrict__ out)
{
    __shared__ float ks[16][7][72];   // 32256 B; cols 0-3 & 68-71 stay zero
    __shared__ float qs[16][64];      // 4 KB
    __shared__ float lg[NP][64];      // 12544 B
    __shared__ float dn[64];

    const int b   = blockIdx.x >> 6;
    const int h   = blockIdx.x & 63;
    const int tid = threadIdx.x;
    const int s   = tid >> 6;
    const int w   = tid & 63;

    const float* qp = qkv + (size_t)b*CHW;
    const float* kp = qkv + BCHW + (size_t)b*CHW;
    const float* vp = qkv + (size_t)2*BCHW + (size_t)b*CHW;

    // zero halo columns (persists: data writes never touch cols 0-3/68-71)
    if (tid < 224) {
        int cr  = tid % 112;
        int c   = cr / 7, r = cr % 7;
        int col = (tid < 112) ? 0 : 68;
        *(float4*)&ks[c][r][col] = make_float4(0.f, 0.f, 0.f, 0.f);
    }

    // per-wave position range
    const int p0 = (NP * s) >> 2;          // 0,12,24,36
    const int p1 = (NP * (s + 1)) >> 2;    // 12,24,36,49
    const int np = p1 - p0;
    int offs[13];
    #pragma unroll
    for (int j = 0; j < 13; ++j) {
        int p = p0 + j; if (p > NP - 1) p = NP - 1;
        offs[j] = (p / 7) * 72 + (p % 7);
    }

    float accp[13];
    #pragma unroll
    for (int j = 0; j < 13; ++j) accp[j] = 0.f;

    float4 stg[7];
    float4 qstg;
    load_chunk(kp, h, 0, stg);
    {
        int c = tid >> 4, q4 = (tid & 15) << 2;
        qstg = *(const float4*)&qp[(size_t)c*HWSZ + h*WW_ + q4];
    }

    // -------- Phase A: logits --------
    for (int ck = 0; ck < 8; ++ck) {
        store_chunk(ks, stg);
        {
            int c = tid >> 4, q4 = (tid & 15) << 2;
            *(float4*)&qs[c][q4] = qstg;
        }
        __syncthreads();
        if (ck < 7) {
            load_chunk(kp, h, (ck + 1) * 16, stg);
            int c = tid >> 4, q4 = (tid & 15) << 2;
            qstg = *(const float4*)&qp[(size_t)((ck + 1)*16 + c)*HWSZ + h*WW_ + q4];
        }
        float qreg[16];
        const float* qb = &qs[0][w];
        #pragma unroll
        for (int ci = 0; ci < 16; ++ci) qreg[ci] = qb[ci * 64];
        const float* kb = &ks[0][0][w + 1];
        #pragma unroll
        for (int j = 0; j < 13; ++j) {
            if (j < np) {
                const float* kr = kb + offs[j];
                #pragma unroll
                for (int ci = 0; ci < 16; ++ci)
                    accp[j] = fmaf(qreg[ci], kr[ci * 504], accp[j]);
            }
        }
        __syncthreads();
    }
    #pragma unroll
    for (int j = 0; j < 13; ++j)
        if (j < np) lg[p0 + j][w] = accp[j];
    __syncthreads();

    // -------- Phase B: softmax (wave 0; OOB logits are exactly 0, included) --
    if (tid < 64) {
        float tv[NP];
        float m = -1e30f;
        #pragma unroll
        for (int p = 0; p < NP; ++p) { tv[p] = lg[p][tid]; m = fmaxf(m, tv[p]); }
        float d = 0.f;
        #pragma unroll
        for (int p = 0; p < NP; ++p) {
            float e = __expf(tv[p] - m);
            d += e;
            lg[p][tid] = e;
        }
        dn[tid] = 1.f / d;
    }
    __syncthreads();

    // -------- Phase C: y = attn . v --------
    float a[NP];
    #pragma unroll
    for (int p = 0; p < NP; ++p) a[p] = lg[p][w];
    const float sc = dn[w];
    #pragma unroll
    for (int p = 0; p < NP; ++p) a[p] *= sc;

    load_chunk(vp, h, 0, stg);
    const int cbase = s << 2;
    for (int ck = 0; ck < 8; ++ck) {
        store_chunk(ks, stg);
        __syncthreads();
        if (ck < 7) load_chunk(vp, h, (ck + 1) * 16, stg);
        const float* kb = &ks[0][0][w + 1];
        #pragma unroll
        for (int ci = 0; ci < 4; ++ci) {
            const float* kr = kb + (cbase + ci) * 504;
            float acc = 0.f;
            #pragma unroll
            for (int p = 0; p < NP; ++p)
                acc = fmaf(a[p], kr[(p / 7) * 72 + (p % 7)], acc);
            out[(size_t)b*CHW + (size_t)(ck*16 + cbase + ci)*HWSZ + h*WW_ + w] = acc;
        }
        __syncthreads();
    }
}

extern "C" void kernel_launch(void* const* d_in, const int* in_sizes, int n_in,
                              void* d_out, int out_size, void* d_ws, size_t ws_size,
                              hipStream_t stream) {
    const float* x  = (const float*)d_in[0];
    const float* Wq = (const float*)d_in[1];
    const float* bq = (const float*)d_in[2];
    const float* Wk = (const float*)d_in[3];
    const float* bk = (const float*)d_in[4];
    const float* Wv = (const float*)d_in[5];
    const float* bv = (const float*)d_in[6];
    float* out = (float*)d_out;
    float* qkv = (float*)d_ws;   // 3*BCHW*4 = 50.3 MB scratch

    qkv_proj<<<dim3(256, 6), 128, 0, stream>>>(x, Wq, bq, Wk, bk, Wv, bv, qkv);
    locatt  <<<BB*HH_, 256, 0, stream>>>(qkv, out);
}

// Round 3
// 150.755 us; speedup vs baseline: 4.3932x; 1.0766x over previous
//
#include <hip/hip_runtime.h>

#define CC   128
#define HH_  64
#define WW_  64
#define BB   8
#define HWSZ (HH_*WW_)      // 4096
#define CHW  (CC*HWSZ)      // 524288
#define BCHW (BB*CHW)       // 4194304
#define PAD  3
#define NP   49

// ================= Kernel 1: q/k/v = W*x + b as register-tiled GEMM =========
__global__ __launch_bounds__(128) void qkv_proj(
    const float* __restrict__ x,
    const float* __restrict__ Wq, const float* __restrict__ bq,
    const float* __restrict__ Wk, const float* __restrict__ bk,
    const float* __restrict__ Wv, const float* __restrict__ bv,
    float* __restrict__ qkv)   // [3][B][C][H][W]
{
    __shared__ float xs[32][132];
    __shared__ float ws[32][68];
    const int pt  = blockIdx.x;
    const int og  = blockIdx.y;
    const int b   = pt >> 5;
    const int hw0 = (pt & 31) << 7;
    const int tid = threadIdx.x;

    const int proj = og >> 1;
    const int row0 = (og & 1) << 6;
    const float* Wp = (proj == 0) ? Wq : (proj == 1 ? Wk : Wv);
    const float* Bp = (proj == 0) ? bq : (proj == 1 ? bk : bv);

    const int o8  = (tid >> 4) << 3;
    const int px4 = (tid & 15) << 2;

    float acc[8][8];
    #pragma unroll
    for (int j = 0; j < 8; ++j) {
        float bj = Bp[row0 + o8 + j];
        #pragma unroll
        for (int i = 0; i < 8; ++i) acc[j][i] = bj;
    }

    const float* xb = x + (size_t)b*CHW + hw0;

    for (int ck = 0; ck < 4; ++ck) {
        const int c0 = ck << 5;
        __syncthreads();
        #pragma unroll
        for (int i = 0; i < 8; ++i) {
            int f  = tid + (i << 7);
            int c  = f >> 5, q4 = (f & 31) << 2;
            *(float4*)&xs[c][q4] = *(const float4*)&xb[(size_t)(c0 + c)*HWSZ + q4];
        }
        #pragma unroll
        for (int i = 0; i < 4; ++i) {
            int f = tid + (i << 7);
            int o = f >> 3, c4 = (f & 7) << 2;
            float4 wv = *(const float4*)&Wp[(size_t)(row0 + o)*CC + c0 + c4];
            ws[c4+0][o] = wv.x; ws[c4+1][o] = wv.y;
            ws[c4+2][o] = wv.z; ws[c4+3][o] = wv.w;
        }
        __syncthreads();

        #pragma unroll 8
        for (int c = 0; c < 32; ++c) {
            float4 w0 = *(const float4*)&ws[c][o8];
            float4 w1 = *(const float4*)&ws[c][o8 + 4];
            float4 x0 = *(const float4*)&xs[c][px4];
            float4 x1 = *(const float4*)&xs[c][px4 + 64];
            float wr[8] = {w0.x,w0.y,w0.z,w0.w,w1.x,w1.y,w1.z,w1.w};
            float xr[8] = {x0.x,x0.y,x0.z,x0.w,x1.x,x1.y,x1.z,x1.w};
            #pragma unroll
            for (int j = 0; j < 8; ++j)
                #pragma unroll
                for (int i = 0; i < 8; ++i)
                    acc[j][i] = fmaf(wr[j], xr[i], acc[j][i]);
        }
    }

    float* op = qkv + (size_t)proj*BCHW + (size_t)b*CHW + hw0;
    #pragma unroll
    for (int j = 0; j < 8; ++j) {
        const int row = row0 + o8 + j;
        float4 s0 = make_float4(acc[j][0], acc[j][1], acc[j][2], acc[j][3]);
        float4 s1 = make_float4(acc[j][4], acc[j][5], acc[j][6], acc[j][7]);
        *(float4*)&op[(size_t)row*HWSZ + px4]      = s0;
        *(float4*)&op[(size_t)row*HWSZ + px4 + 64] = s1;
    }
}

// ================= Kernel 2: local attention, 2-row tiles ===================
// Block = (b, h0..h0+1), 512 thr (8 waves), lane = pixel w. XCD swizzle: h
// groups pinned to XCDs so halo rows are shared in L2.
// k/v streamed in 16-ch x 8-row chunks through ks[16][8][72] (halo cols
// permanently zero). Each LDS element feeds both output rows (~2 FMA/read).
// Phase A: wave s owns k-row r=s -> 7 dx-accumulators per output row; logit
// position p uses exactly one k-row, so no cross-wave reduction.
// Phase C: wave s owns channels {s, s+8}; both rows share each v read.
__device__ __forceinline__ void load_chunk8(const float* __restrict__ src,
                                            int h0, int c0, float4* stg) {
    const int tid = threadIdx.x;
    #pragma unroll
    for (int i = 0; i < 4; ++i) {
        int f   = tid + (i << 9);           // 0..2047 = 16ch * 8r * 16quads
        int c   = f >> 7;
        int rem = f & 127;
        int r   = rem >> 4;
        int q4  = (rem & 15) << 2;
        int hh  = h0 - PAD + r;
        if ((unsigned)hh < (unsigned)HH_)
            stg[i] = *(const float4*)&src[(size_t)(c0 + c)*HWSZ + hh*WW_ + q4];
        else
            stg[i] = make_float4(0.f, 0.f, 0.f, 0.f);
    }
}

__device__ __forceinline__ void store_chunk8(float (*ks)[8][72], const float4* stg) {
    const int tid = threadIdx.x;
    #pragma unroll
    for (int i = 0; i < 4; ++i) {
        int f   = tid + (i << 9);
        int c   = f >> 7;
        int rem = f & 127;
        int r   = rem >> 4;
        int q4  = (rem & 15) << 2;
        *(float4*)&ks[c][r][4 + q4] = stg[i];
    }
}

__global__ __launch_bounds__(512) void locatt(
    const float* __restrict__ qkv, float* __restrict__ out)
{
    __shared__ float ks[16][8][72];   // 36864 B; cols 0-3 & 68-71 stay zero
    __shared__ float lg[2][NP][64];   // 25088 B
    __shared__ float dn[2][64];

    // XCD swizzle: XCD = blk%8 gets h2-tiles [x*4, x*4+4) for every b
    const int blk = blockIdx.x;
    const int x   = blk & 7;
    const int j   = blk >> 3;
    const int b   = j >> 2;
    const int h0  = (((x << 2) | (j & 3)) << 1);   // 2-row tile origin
    const int tid = threadIdx.x;
    const int s   = tid >> 6;   // wave 0..7
    const int w   = tid & 63;   // pixel col

    const float* qp = qkv + (size_t)b*CHW;
    const float* kp = qkv + (size_t)BCHW + (size_t)b*CHW;
    const float* vp = qkv + (size_t)2*BCHW + (size_t)b*CHW;

    // zero halo columns once (data stores never touch cols 0-3 / 68-71)
    if (tid < 256) {
        int idx = tid & 127;
        int c = idx >> 3, r = idx & 7;
        int col = (tid < 128) ? 0 : 68;
        *(float4*)&ks[c][r][col] = make_float4(0.f, 0.f, 0.f, 0.f);
    }

    const bool do0 = (s < 7);   // k-row s serves row0 positions p = s*7+dx
    const bool do1 = (s >= 1);  // and row1 positions p = (s-1)*7+dx

    float acc0[7], acc1[7];
    #pragma unroll
    for (int dx = 0; dx < 7; ++dx) { acc0[dx] = 0.f; acc1[dx] = 0.f; }

    float4 stg[4];
    load_chunk8(kp, h0, 0, stg);

    // -------- Phase A: logits --------
    for (int ck = 0; ck < 8; ++ck) {
        store_chunk8(ks, stg);
        __syncthreads();
        if (ck < 7) load_chunk8(kp, h0, (ck + 1) * 16, stg);

        const int c0 = ck << 4;
        float q0[16], q1[16];
        #pragma unroll
        for (int ci = 0; ci < 16; ++ci) {
            const float* qc = qp + (size_t)(c0 + ci)*HWSZ + h0*WW_ + w;
            q0[ci] = do0 ? qc[0]   : 0.f;   // L1-broadcast across waves
            q1[ci] = do1 ? qc[WW_] : 0.f;
        }

        const float* kbase = &ks[0][s][w + 1];
        #pragma unroll
        for (int ci = 0; ci < 16; ++ci) {
            const float* kc = kbase + ci * 576;   // ks[ci][s][w+1]
            #pragma unroll
            for (int dx = 0; dx < 7; ++dx) {
                float kv = kc[dx];
                acc0[dx] = fmaf(q0[ci], kv, acc0[dx]);
                acc1[dx] = fmaf(q1[ci], kv, acc1[dx]);
            }
        }
        __syncthreads();
    }

    #pragma unroll
    for (int dx = 0; dx < 7; ++dx) {
        if (do0) lg[0][s*7 + dx][w]       = acc0[dx];
        if (do1) lg[1][(s-1)*7 + dx][w]   = acc1[dx];
    }
    load_chunk8(vp, h0, 0, stg);   // v chunk 0 flies during softmax
    __syncthreads();

    // -------- Phase B: two softmaxes (OOB logits exactly 0, included) ------
    if (tid < 128) {
        const int r = tid >> 6, px = tid & 63;
        float tv[NP];
        float m = -1e30f;
        #pragma unroll
        for (int p = 0; p < NP; ++p) { tv[p] = lg[r][p][px]; m = fmaxf(m, tv[p]); }
        float d = 0.f;
        #pragma unroll
        for (int p = 0; p < NP; ++p) {
            float e = __expf(tv[p] - m);
            d += e;
            lg[r][p][px] = e;
        }
        dn[r][px] = 1.f / d;
    }
    __syncthreads();

    // -------- Phase C: y = attn . v --------
    float a0[NP], a1[NP];
    const float sc0 = dn[0][w], sc1 = dn[1][w];
    #pragma unroll
    for (int p = 0; p < NP; ++p) a0[p] = lg[0][p][w] * sc0;
    #pragma unroll
    for (int p = 0; p < NP; ++p) a1[p] = lg[1][p][w] * sc1;

    for (int ck = 0; ck < 8; ++ck) {
        store_chunk8(ks, stg);
        __syncthreads();
        if (ck < 7) load_chunk8(vp, h0, (ck + 1) * 16, stg);

        #pragma unroll
        for (int half = 0; half < 2; ++half) {
            const int cl = s + (half << 3);
            float y0 = 0.f, y1 = 0.f;
            #pragma unroll
            for (int r = 0; r < 8; ++r) {
                const float* vr = &ks[cl][r][w + 1];
                #pragma unroll
                for (int dx = 0; dx < 7; ++dx) {
                    float vv = vr[dx];
                    if (r < 7)  y0 = fmaf(a0[r*7 + dx], vv, y0);       // row0
                    if (r >= 1) y1 = fmaf(a1[(r-1)*7 + dx], vv, y1);   // row1
                }
            }
            float* op = out + (size_t)b*CHW + (size_t)(ck*16 + cl)*HWSZ
                            + (size_t)h0*WW_ + w;
            op[0]   = y0;
            op[WW_] = y1;
        }
        __syncthreads();
    }
}

extern "C" void kernel_launch(void* const* d_in, const int* in_sizes, int n_in,
                              void* d_out, int out_size, void* d_ws, size_t ws_size,
                              hipStream_t stream) {
    const float* x  = (const float*)d_in[0];
    const float* Wq = (const float*)d_in[1];
    const float* bq = (const float*)d_in[2];
    const float* Wk = (const float*)d_in[3];
    const float* bk = (const float*)d_in[4];
    const float* Wv = (const float*)d_in[5];
    const float* bv = (const float*)d_in[6];
    float* out = (float*)d_out;
    float* qkv = (float*)d_ws;   // 3*BCHW*4 = 50.3 MB scratch

    qkv_proj<<<dim3(256, 6), 128, 0, stream>>>(x, Wq, bq, Wk, bk, Wv, bv, qkv);
    locatt  <<<256, 512, 0, stream>>>(qkv, out);
}

// Round 4
// 144.598 us; speedup vs baseline: 4.5802x; 1.0426x over previous
//
#include <hip/hip_runtime.h>
#include <hip/hip_bf16.h>

#define CC   128
#define HH_  64
#define WW_  64
#define BB   8
#define HWSZ (HH_*WW_)      // 4096
#define CHW  (CC*HWSZ)      // 524288
#define BCHW (BB*CHW)       // 4194304
#define PAD  3
#define NP   49

typedef __attribute__((ext_vector_type(8))) short short8;
typedef __attribute__((ext_vector_type(4))) float float4v;

// ============ Kernel 0: W -> bf16 hi/lo split (into d_out scratch) ==========
__global__ __launch_bounds__(256) void prep_w(
    const float* __restrict__ Wq, const float* __restrict__ Wk,
    const float* __restrict__ Wv,
    unsigned short* __restrict__ whi, unsigned short* __restrict__ wlo)
{
    int i = blockIdx.x * 256 + threadIdx.x;          // 0..49151
    const float* src = (i < 16384) ? Wq : (i < 32768 ? Wk : Wv);
    float f = src[i & 16383];
    __hip_bfloat16 h = __float2bfloat16(f);
    float hf = __bfloat162float(h);
    __hip_bfloat16 l = __float2bfloat16(f - hf);
    unsigned short hu, lu;
    __builtin_memcpy(&hu, &h, 2);
    __builtin_memcpy(&lu, &l, 2);
    whi[i] = hu;
    wlo[i] = lu;
}

// ============ Kernel 1: q/k/v GEMM via split-bf16 MFMA ======================
// Grid (256 px-tiles, 3 proj), 256 thr (4 waves, 2x2). Block tile: 128 out x
// 128 px, K' = 3 passes x 128 (hi*hi, hi*lo, lo*hi). Fragment pattern = m97's
// verified gemm_bt: A[m=lane&15][k=(lane>>4)*8+j] from global bf16 W (L1-hot),
// B = xT[n][k] from LDS (converted+transposed in-kernel), D row=(lane>>4)*4+r,
// col=lane&15. Bias folded into acc init. One barrier total.
__global__ __launch_bounds__(256, 2) void qkv_mfma(
    const float* __restrict__ x,
    const unsigned short* __restrict__ whi, const unsigned short* __restrict__ wlo,
    const float* __restrict__ bq, const float* __restrict__ bk,
    const float* __restrict__ bv, float* __restrict__ qkv)
{
    __shared__ unsigned short xT[2][128][136];   // [hi/lo][px][c], 69632 B
    const int proj = blockIdx.y;
    const int n0g  = blockIdx.x << 7;
    const int b    = n0g >> 12;
    const int npx  = n0g & 4095;
    const int tid  = threadIdx.x;
    const int lane = tid & 63;
    const int wv   = tid >> 6;
    const int wm   = wv & 1, wn = wv >> 1;

    // ---- stage x tile: 128 c x 128 px, convert to hi/lo bf16, transpose ----
    const float* xb = x + (size_t)b*CHW + npx;
    #pragma unroll
    for (int it = 0; it < 16; ++it) {
        int f  = tid + (it << 8);       // 0..4095
        int c  = f >> 5;                // 0..127
        int p4 = (f & 31) << 2;         // px quad
        float4 v = *(const float4*)&xb[(size_t)c*HWSZ + p4];
        float vv[4] = {v.x, v.y, v.z, v.w};
        #pragma unroll
        for (int u = 0; u < 4; ++u) {
            __hip_bfloat16 h = __float2bfloat16(vv[u]);
            float hf = __bfloat162float(h);
            __hip_bfloat16 l = __float2bfloat16(vv[u] - hf);
            unsigned short hu, lu;
            __builtin_memcpy(&hu, &h, 2);
            __builtin_memcpy(&lu, &l, 2);
            xT[0][p4 + u][c] = hu;
            xT[1][p4 + u][c] = lu;
        }
    }

    // ---- acc init = bias ----
    const float* Bp = (proj == 0) ? bq : (proj == 1 ? bk : bv);
    const int q4 = lane >> 4;
    float4v acc[4][4];
    #pragma unroll
    for (int sm = 0; sm < 4; ++sm) {
        const int mb = wm*64 + sm*16 + q4*4;
        float4v bi;
        bi[0] = Bp[mb+0]; bi[1] = Bp[mb+1]; bi[2] = Bp[mb+2]; bi[3] = Bp[mb+3];
        #pragma unroll
        for (int sn = 0; sn < 4; ++sn) acc[sm][sn] = bi;
    }

    __syncthreads();

    // ---- K loop: 3 passes x 4 chunks of 32 ----
    const unsigned short* Wh = whi + (size_t)proj*16384;
    const unsigned short* Wl = wlo + (size_t)proj*16384;
    const int kq8  = q4 << 3;        // 0,8,16,24
    const int mrow = lane & 15;

    for (int pass = 0; pass < 3; ++pass) {
        const unsigned short* Wp = (pass == 2) ? Wl : Wh;
        const int xi = (pass == 1) ? 1 : 0;
        #pragma unroll
        for (int kc = 0; kc < 4; ++kc) {
            const int kb = kc << 5;
            short8 a[4], bf[4];
            #pragma unroll
            for (int sm = 0; sm < 4; ++sm) {
                const int m = wm*64 + sm*16 + mrow;
                a[sm] = *(const short8*)&Wp[(size_t)m*CC + kb + kq8];
            }
            #pragma unroll
            for (int sn = 0; sn < 4; ++sn) {
                const int n = wn*64 + sn*16 + mrow;
                bf[sn] = *(const short8*)&xT[xi][n][kb + kq8];
            }
            #pragma unroll
            for (int sm = 0; sm < 4; ++sm)
                #pragma unroll
                for (int sn = 0; sn < 4; ++sn)
                    acc[sm][sn] = __builtin_amdgcn_mfma_f32_16x16x32_bf16(
                        a[sm], bf[sn], acc[sm][sn], 0, 0, 0);
        }
    }

    // ---- epilogue ----
    float* op = qkv + (size_t)proj*BCHW + (size_t)b*CHW + npx;
    #pragma unroll
    for (int sm = 0; sm < 4; ++sm) {
        const int mb = wm*64 + sm*16 + q4*4;
        #pragma unroll
        for (int sn = 0; sn < 4; ++sn) {
            const int n = wn*64 + sn*16 + mrow;
            #pragma unroll
            for (int r = 0; r < 4; ++r)
                op[(size_t)(mb + r)*HWSZ + n] = acc[sm][sn][r];
        }
    }
}

// ================= Kernel 2: local attention, 2-row tiles (unchanged) =======
__device__ __forceinline__ void load_chunk8(const float* __restrict__ src,
                                            int h0, int c0, float4* stg) {
    const int tid = threadIdx.x;
    #pragma unroll
    for (int i = 0; i < 4; ++i) {
        int f   = tid + (i << 9);           // 0..2047 = 16ch * 8r * 16quads
        int c   = f >> 7;
        int rem = f & 127;
        int r   = rem >> 4;
        int q4  = (rem & 15) << 2;
        int hh  = h0 - PAD + r;
        if ((unsigned)hh < (unsigned)HH_)
            stg[i] = *(const float4*)&src[(size_t)(c0 + c)*HWSZ + hh*WW_ + q4];
        else
            stg[i] = make_float4(0.f, 0.f, 0.f, 0.f);
    }
}

__device__ __forceinline__ void store_chunk8(float (*ks)[8][72], const float4* stg) {
    const int tid = threadIdx.x;
    #pragma unroll
    for (int i = 0; i < 4; ++i) {
        int f   = tid + (i << 9);
        int c   = f >> 7;
        int rem = f & 127;
        int r   = rem >> 4;
        int q4  = (rem & 15) << 2;
        *(float4*)&ks[c][r][4 + q4] = stg[i];
    }
}

__global__ __launch_bounds__(512) void locatt(
    const float* __restrict__ qkv, float* __restrict__ out)
{
    __shared__ float ks[16][8][72];   // 36864 B; cols 0-3 & 68-71 stay zero
    __shared__ float lg[2][NP][64];   // 25088 B
    __shared__ float dn[2][64];

    const int blk = blockIdx.x;
    const int x   = blk & 7;
    const int j   = blk >> 3;
    const int b   = j >> 2;
    const int h0  = (((x << 2) | (j & 3)) << 1);
    const int tid = threadIdx.x;
    const int s   = tid >> 6;
    const int w   = tid & 63;

    const float* qp = qkv + (size_t)b*CHW;
    const float* kp = qkv + (size_t)BCHW + (size_t)b*CHW;
    const float* vp = qkv + (size_t)2*BCHW + (size_t)b*CHW;

    if (tid < 256) {
        int idx = tid & 127;
        int c = idx >> 3, r = idx & 7;
        int col = (tid < 128) ? 0 : 68;
        *(float4*)&ks[c][r][col] = make_float4(0.f, 0.f, 0.f, 0.f);
    }

    const bool do0 = (s < 7);
    const bool do1 = (s >= 1);

    float acc0[7], acc1[7];
    #pragma unroll
    for (int dx = 0; dx < 7; ++dx) { acc0[dx] = 0.f; acc1[dx] = 0.f; }

    float4 stg[4];
    load_chunk8(kp, h0, 0, stg);

    for (int ck = 0; ck < 8; ++ck) {
        store_chunk8(ks, stg);
        __syncthreads();
        if (ck < 7) load_chunk8(kp, h0, (ck + 1) * 16, stg);

        const int c0 = ck << 4;
        float q0[16], q1[16];
        #pragma unroll
        for (int ci = 0; ci < 16; ++ci) {
            const float* qc = qp + (size_t)(c0 + ci)*HWSZ + h0*WW_ + w;
            q0[ci] = do0 ? qc[0]   : 0.f;
            q1[ci] = do1 ? qc[WW_] : 0.f;
        }

        const float* kbase = &ks[0][s][w + 1];
        #pragma unroll
        for (int ci = 0; ci < 16; ++ci) {
            const float* kc = kbase + ci * 576;
            #pragma unroll
            for (int dx = 0; dx < 7; ++dx) {
                float kv = kc[dx];
                acc0[dx] = fmaf(q0[ci], kv, acc0[dx]);
                acc1[dx] = fmaf(q1[ci], kv, acc1[dx]);
            }
        }
        __syncthreads();
    }

    #pragma unroll
    for (int dx = 0; dx < 7; ++dx) {
        if (do0) lg[0][s*7 + dx][w]     = acc0[dx];
        if (do1) lg[1][(s-1)*7 + dx][w] = acc1[dx];
    }
    load_chunk8(vp, h0, 0, stg);
    __syncthreads();

    if (tid < 128) {
        const int r = tid >> 6, px = tid & 63;
        float tv[NP];
        float m = -1e30f;
        #pragma unroll
        for (int p = 0; p < NP; ++p) { tv[p] = lg[r][p][px]; m = fmaxf(m, tv[p]); }
        float d = 0.f;
        #pragma unroll
        for (int p = 0; p < NP; ++p) {
            float e = __expf(tv[p] - m);
            d += e;
            lg[r][p][px] = e;
        }
        dn[r][px] = 1.f / d;
    }
    __syncthreads();

    float a0[NP], a1[NP];
    const float sc0 = dn[0][w], sc1 = dn[1][w];
    #pragma unroll
    for (int p = 0; p < NP; ++p) a0[p] = lg[0][p][w] * sc0;
    #pragma unroll
    for (int p = 0; p < NP; ++p) a1[p] = lg[1][p][w] * sc1;

    for (int ck = 0; ck < 8; ++ck) {
        store_chunk8(ks, stg);
        __syncthreads();
        if (ck < 7) load_chunk8(vp, h0, (ck + 1) * 16, stg);

        #pragma unroll
        for (int half = 0; half < 2; ++half) {
            const int cl = s + (half << 3);
            float y0 = 0.f, y1 = 0.f;
            #pragma unroll
            for (int r = 0; r < 8; ++r) {
                const float* vr = &ks[cl][r][w + 1];
                #pragma unroll
                for (int dx = 0; dx < 7; ++dx) {
                    float vv = vr[dx];
                    if (r < 7)  y0 = fmaf(a0[r*7 + dx], vv, y0);
                    if (r >= 1) y1 = fmaf(a1[(r-1)*7 + dx], vv, y1);
                }
            }
            float* op = out + (size_t)b*CHW + (size_t)(ck*16 + cl)*HWSZ
                            + (size_t)h0*WW_ + w;
            op[0]   = y0;
            op[WW_] = y1;
        }
        __syncthreads();
    }
}

extern "C" void kernel_launch(void* const* d_in, const int* in_sizes, int n_in,
                              void* d_out, int out_size, void* d_ws, size_t ws_size,
                              hipStream_t stream) {
    const float* x  = (const float*)d_in[0];
    const float* Wq = (const float*)d_in[1];
    const float* bq = (const float*)d_in[2];
    const float* Wk = (const float*)d_in[3];
    const float* bk = (const float*)d_in[4];
    const float* Wv = (const float*)d_in[5];
    const float* bv = (const float*)d_in[6];
    float* out = (float*)d_out;
    float* qkv = (float*)d_ws;   // 3*BCHW*4 = 50.3 MB scratch

    // d_out doubles as scratch for bf16 W (196 KB); fully overwritten by
    // locatt afterwards (stream-ordered), so this is safe under re-poisoning.
    unsigned short* whi = (unsigned short*)d_out;
    unsigned short* wlo = whi + 3*16384;

    prep_w  <<<192, 256, 0, stream>>>(Wq, Wk, Wv, whi, wlo);
    qkv_mfma<<<dim3(256, 3), 256, 0, stream>>>(x, whi, wlo, bq, bk, bv, qkv);
    locatt  <<<256, 512, 0, stream>>>(qkv, out);
}

// Round 5
// 144.355 us; speedup vs baseline: 4.5880x; 1.0017x over previous
//
#include <hip/hip_runtime.h>
#include <hip/hip_bf16.h>

#define CC   128
#define HH_  64
#define WW_  64
#define BB   8
#define HWSZ (HH_*WW_)      // 4096
#define CHW  (CC*HWSZ)      // 524288
#define BCHW (BB*CHW)       // 4194304
#define PAD  3
#define NP   49

typedef __attribute__((ext_vector_type(8))) short short8;
typedef __attribute__((ext_vector_type(4))) float float4v;

// ============ Kernel 0: W -> bf16 hi/lo split (into d_out scratch) ==========
__global__ __launch_bounds__(256) void prep_w(
    const float* __restrict__ Wq, const float* __restrict__ Wk,
    const float* __restrict__ Wv,
    unsigned short* __restrict__ whi, unsigned short* __restrict__ wlo)
{
    int i = blockIdx.x * 256 + threadIdx.x;          // 0..49151
    const float* src = (i < 16384) ? Wq : (i < 32768 ? Wk : Wv);
    float f = src[i & 16383];
    __hip_bfloat16 h = __float2bfloat16(f);
    float hf = __bfloat162float(h);
    __hip_bfloat16 l = __float2bfloat16(f - hf);
    unsigned short hu, lu;
    __builtin_memcpy(&hu, &h, 2);
    __builtin_memcpy(&lu, &l, 2);
    whi[i] = hu;
    wlo[i] = lu;
}

// ============ Kernel 1: q/k/v GEMM via split-bf16 MFMA (unchanged r4) =======
__global__ __launch_bounds__(256, 2) void qkv_mfma(
    const float* __restrict__ x,
    const unsigned short* __restrict__ whi, const unsigned short* __restrict__ wlo,
    const float* __restrict__ bq, const float* __restrict__ bk,
    const float* __restrict__ bv, float* __restrict__ qkv)
{
    __shared__ unsigned short xT[2][128][136];   // [hi/lo][px][c], 69632 B
    const int proj = blockIdx.y;
    const int n0g  = blockIdx.x << 7;
    const int b    = n0g >> 12;
    const int npx  = n0g & 4095;
    const int tid  = threadIdx.x;
    const int lane = tid & 63;
    const int wv   = tid >> 6;
    const int wm   = wv & 1, wn = wv >> 1;

    const float* xb = x + (size_t)b*CHW + npx;
    #pragma unroll
    for (int it = 0; it < 16; ++it) {
        int f  = tid + (it << 8);       // 0..4095
        int c  = f >> 5;                // 0..127
        int p4 = (f & 31) << 2;         // px quad
        float4 v = *(const float4*)&xb[(size_t)c*HWSZ + p4];
        float vv[4] = {v.x, v.y, v.z, v.w};
        #pragma unroll
        for (int u = 0; u < 4; ++u) {
            __hip_bfloat16 h = __float2bfloat16(vv[u]);
            float hf = __bfloat162float(h);
            __hip_bfloat16 l = __float2bfloat16(vv[u] - hf);
            unsigned short hu, lu;
            __builtin_memcpy(&hu, &h, 2);
            __builtin_memcpy(&lu, &l, 2);
            xT[0][p4 + u][c] = hu;
            xT[1][p4 + u][c] = lu;
        }
    }

    const float* Bp = (proj == 0) ? bq : (proj == 1 ? bk : bv);
    const int q4 = lane >> 4;
    float4v acc[4][4];
    #pragma unroll
    for (int sm = 0; sm < 4; ++sm) {
        const int mb = wm*64 + sm*16 + q4*4;
        float4v bi;
        bi[0] = Bp[mb+0]; bi[1] = Bp[mb+1]; bi[2] = Bp[mb+2]; bi[3] = Bp[mb+3];
        #pragma unroll
        for (int sn = 0; sn < 4; ++sn) acc[sm][sn] = bi;
    }

    __syncthreads();

    const unsigned short* Wh = whi + (size_t)proj*16384;
    const unsigned short* Wl = wlo + (size_t)proj*16384;
    const int kq8  = q4 << 3;
    const int mrow = lane & 15;

    for (int pass = 0; pass < 3; ++pass) {
        const unsigned short* Wp = (pass == 2) ? Wl : Wh;
        const int xi = (pass == 1) ? 1 : 0;
        #pragma unroll
        for (int kc = 0; kc < 4; ++kc) {
            const int kb = kc << 5;
            short8 a[4], bf[4];
            #pragma unroll
            for (int sm = 0; sm < 4; ++sm) {
                const int m = wm*64 + sm*16 + mrow;
                a[sm] = *(const short8*)&Wp[(size_t)m*CC + kb + kq8];
            }
            #pragma unroll
            for (int sn = 0; sn < 4; ++sn) {
                const int n = wn*64 + sn*16 + mrow;
                bf[sn] = *(const short8*)&xT[xi][n][kb + kq8];
            }
            #pragma unroll
            for (int sm = 0; sm < 4; ++sm)
                #pragma unroll
                for (int sn = 0; sn < 4; ++sn)
                    acc[sm][sn] = __builtin_amdgcn_mfma_f32_16x16x32_bf16(
                        a[sm], bf[sn], acc[sm][sn], 0, 0, 0);
        }
    }

    float* op = qkv + (size_t)proj*BCHW + (size_t)b*CHW + npx;
    #pragma unroll
    for (int sm = 0; sm < 4; ++sm) {
        const int mb = wm*64 + sm*16 + q4*4;
        #pragma unroll
        for (int sn = 0; sn < 4; ++sn) {
            const int n = wn*64 + sn*16 + mrow;
            #pragma unroll
            for (int r = 0; r < 4; ++r)
                op[(size_t)(mb + r)*HWSZ + n] = acc[sm][sn][r];
        }
    }
}

// ================= Kernel 2: local attention v3 =============================
// Block = (b, h0..h0+1), 512 thr (8 waves). XCD swizzle kept.
// Phase A: lane=(csub 0..3, q16 0..15). Wave s <-> k-row s. Per (channel,row):
//   3x ds_read_b128 window [w4-4,w4+8) -> 56 FMA (4px x 7dx x 2 rows).
//   q read direct from global (L1 broadcast). csub-partials reduced by
//   shfl_xor(16)+shfl_xor(32).
// Phase C: v staged channel-interleaved vT[r][72][17] (odd pad -> no bank
//   conflicts); lane=w, wave s owns chunk channels {2s,2s+1}; per (r,dx) two
//   adjacent dwords (ds_read2) feed 4 FMA; attn in 98 regs.
__device__ __forceinline__ void load_chunk8(const float* __restrict__ src,
                                            int h0, int c0, float4* stg) {
    const int tid = threadIdx.x;
    #pragma unroll
    for (int i = 0; i < 4; ++i) {
        int f   = tid + (i << 9);           // 0..2047 = 16ch * 8r * 16quads
        int c   = f >> 7;
        int rem = f & 127;
        int r   = rem >> 4;
        int q4  = (rem & 15) << 2;
        int hh  = h0 - PAD + r;
        if ((unsigned)hh < (unsigned)HH_)
            stg[i] = *(const float4*)&src[(size_t)(c0 + c)*HWSZ + hh*WW_ + q4];
        else
            stg[i] = make_float4(0.f, 0.f, 0.f, 0.f);
    }
}

__global__ __launch_bounds__(512) void locatt(
    const float* __restrict__ qkv, float* __restrict__ out)
{
    // union: phase A k-tile [16][8][72] (36864B) / phase C vT[8][72][17] (39168B)
    __shared__ __align__(16) float smem[8*72*17];   // 9792 floats
    __shared__ float lg[2][NP][64];                 // 25088 B
    __shared__ float dn[2][64];

    const int blk = blockIdx.x;
    const int xs  = blk & 7;
    const int jj  = blk >> 3;
    const int b   = jj >> 2;
    const int h0  = (((xs << 2) | (jj & 3)) << 1);
    const int tid = threadIdx.x;
    const int s   = tid >> 6;      // wave 0..7
    const int lane = tid & 63;
    const int q16  = lane & 15;
    const int csub = lane >> 4;
    const int w4   = q16 << 2;
    const int w    = lane;         // phase C pixel

    const float* qp = qkv + (size_t)b*CHW;
    const float* kp = qkv + (size_t)BCHW + (size_t)b*CHW;
    const float* vp = qkv + (size_t)2*BCHW + (size_t)b*CHW;

    float (*ks)[8][72] = (float(*)[8][72])smem;

    // zero k halo cols (cols 0-3 & 68-71; data stores touch 4..67 only)
    if (tid < 256) {
        int idx = tid & 127;
        int c = idx >> 3, r = idx & 7;
        int col = (tid < 128) ? 0 : 68;
        *(float4*)&ks[c][r][col] = make_float4(0.f, 0.f, 0.f, 0.f);
    }

    const bool do0 = (s < 7);   // k-row s serves row0 p = s*7+dx
    const bool do1 = (s >= 1);  // and row1 p = (s-1)*7+dx

    float acc0[7][4], acc1[7][4];
    #pragma unroll
    for (int dx = 0; dx < 7; ++dx)
        #pragma unroll
        for (int j = 0; j < 4; ++j) { acc0[dx][j] = 0.f; acc1[dx][j] = 0.f; }

    float4 stg[4];
    load_chunk8(kp, h0, 0, stg);

    // -------- Phase A --------
    for (int ck = 0; ck < 8; ++ck) {
        // store chunk (b128)
        #pragma unroll
        for (int i = 0; i < 4; ++i) {
            int f   = tid + (i << 9);
            int c   = f >> 7;
            int rem = f & 127;
            int r   = rem >> 4;
            int q4  = (rem & 15) << 2;
            *(float4*)&ks[c][r][4 + q4] = stg[i];
        }
        __syncthreads();
        if (ck < 7) load_chunk8(kp, h0, (ck + 1) * 16, stg);

        const int c0 = ck << 4;
        #pragma unroll
        for (int ci4 = 0; ci4 < 4; ++ci4) {
            const int c = (ci4 << 2) + csub;
            const float* qc = qp + (size_t)(c0 + c)*HWSZ + h0*WW_ + w4;
            float4 q0v = do0 ? *(const float4*)qc
                             : make_float4(0.f, 0.f, 0.f, 0.f);
            float4 q1v = do1 ? *(const float4*)(qc + WW_)
                             : make_float4(0.f, 0.f, 0.f, 0.f);
            float4 ka  = *(const float4*)&ks[c][s][w4];
            float4 kb  = *(const float4*)&ks[c][s][w4 + 4];
            float4 kc2 = *(const float4*)&ks[c][s][w4 + 8];
            float kw[12] = {ka.x,ka.y,ka.z,ka.w, kb.x,kb.y,kb.z,kb.w,
                            kc2.x,kc2.y,kc2.z,kc2.w};
            float q0a[4] = {q0v.x,q0v.y,q0v.z,q0v.w};
            float q1a[4] = {q1v.x,q1v.y,q1v.z,q1v.w};
            #pragma unroll
            for (int dx = 0; dx < 7; ++dx)
                #pragma unroll
                for (int j = 0; j < 4; ++j) {
                    float kv = kw[j + dx + 1];   // spatial w4+j+dx-3 -> col w4+j+dx+1
                    acc0[dx][j] = fmaf(q0a[j], kv, acc0[dx][j]);
                    acc1[dx][j] = fmaf(q1a[j], kv, acc1[dx][j]);
                }
        }
        __syncthreads();
    }

    // cross-csub reduce (lanes 0..15 <-> 16..31 <-> 32..47 <-> 48..63)
    #pragma unroll
    for (int dx = 0; dx < 7; ++dx)
        #pragma unroll
        for (int j = 0; j < 4; ++j) {
            acc0[dx][j] += __shfl_xor(acc0[dx][j], 16, 64);
            acc0[dx][j] += __shfl_xor(acc0[dx][j], 32, 64);
            acc1[dx][j] += __shfl_xor(acc1[dx][j], 16, 64);
            acc1[dx][j] += __shfl_xor(acc1[dx][j], 32, 64);
        }
    // write lg (b128), distributed: csub writes dx with (dx&3)==csub
    #pragma unroll
    for (int dx = 0; dx < 7; ++dx) {
        if ((dx & 3) == csub) {
            if (do0) *(float4*)&lg[0][s*7 + dx][w4] =
                make_float4(acc0[dx][0], acc0[dx][1], acc0[dx][2], acc0[dx][3]);
            if (do1) *(float4*)&lg[1][(s-1)*7 + dx][w4] =
                make_float4(acc1[dx][0], acc1[dx][1], acc1[dx][2], acc1[dx][3]);
        }
    }

    // prefetch v chunk 0 (wave s -> chunk channels {2s,2s+1}, all 8 rows)
    float vreg[16];
    {
        #pragma unroll
        for (int i = 0; i < 16; ++i) {
            int c  = 2*s + (i >> 3);
            int r  = i & 7;
            int hh = h0 - PAD + r;
            vreg[i] = ((unsigned)hh < (unsigned)HH_)
                      ? vp[(size_t)c*HWSZ + hh*WW_ + w] : 0.f;
        }
    }
    __syncthreads();

    // -------- Phase B: two softmaxes (OOB logits exactly 0, included) ------
    if (tid < 128) {
        const int r = tid >> 6, px = tid & 63;
        float tv[NP];
        float m = -1e30f;
        #pragma unroll
        for (int p = 0; p < NP; ++p) { tv[p] = lg[r][p][px]; m = fmaxf(m, tv[p]); }
        float d = 0.f;
        #pragma unroll
        for (int p = 0; p < NP; ++p) {
            float e = __expf(tv[p] - m);
            d += e;
            lg[r][p][px] = e;
        }
        dn[r][px] = 1.f / d;
    } else {
        // zero vT halo cols {0..3, 68..71} x 8r x 16 slots (1024 floats)
        int t = tid - 128;
        for (int i = t; i < 1024; i += 384) {
            int r    = i >> 7;
            int rem  = i & 127;
            int colg = rem >> 4;
            int col  = (colg < 4) ? colg : (64 + colg);
            smem[r*1224 + col*17 + (rem & 15)] = 0.f;
        }
    }
    __syncthreads();

    // -------- Phase C --------
    float a0[NP], a1[NP];
    const float sc0 = dn[0][w], sc1 = dn[1][w];
    #pragma unroll
    for (int p = 0; p < NP; ++p) a0[p] = lg[0][p][w] * sc0;
    #pragma unroll
    for (int p = 0; p < NP; ++p) a1[p] = lg[1][p][w] * sc1;

    for (int ck = 0; ck < 8; ++ck) {
        // store vreg -> vT[r][4+w][c]  (stride 17 across lanes: conflict-free)
        #pragma unroll
        for (int i = 0; i < 16; ++i) {
            int c = 2*s + (i >> 3);
            int r = i & 7;
            smem[r*1224 + (4 + w)*17 + c] = vreg[i];
        }
        __syncthreads();
        if (ck < 7) {
            int c0v = (ck + 1) << 4;
            #pragma unroll
            for (int i = 0; i < 16; ++i) {
                int c  = 2*s + (i >> 3);
                int r  = i & 7;
                int hh = h0 - PAD + r;
                vreg[i] = ((unsigned)hh < (unsigned)HH_)
                          ? vp[(size_t)(c0v + c)*HWSZ + hh*WW_ + w] : 0.f;
            }
        }
        float y0a = 0.f, y0b = 0.f, y1a = 0.f, y1b = 0.f;
        #pragma unroll
        for (int r = 0; r < 8; ++r) {
            const float* vbase = &smem[r*1224 + (1 + w)*17 + 2*s];
            #pragma unroll
            for (int dx = 0; dx < 7; ++dx) {
                float va = vbase[17*dx];       // channel 2s
                float vb = vbase[17*dx + 1];   // channel 2s+1 (ds_read2 pair)
                if (r < 7) {
                    float aw = a0[r*7 + dx];
                    y0a = fmaf(aw, va, y0a); y0b = fmaf(aw, vb, y0b);
                }
                if (r >= 1) {
                    float aw = a1[(r-1)*7 + dx];
                    y1a = fmaf(aw, va, y1a); y1b = fmaf(aw, vb, y1b);
                }
            }
        }
        float* op = out + (size_t)b*CHW + (size_t)(ck*16 + 2*s)*HWSZ
                        + (size_t)h0*WW_ + w;
        op[0]          = y0a;   // c=2s,   row h0
        op[WW_]        = y1a;   // c=2s,   row h0+1
        op[HWSZ]       = y0b;   // c=2s+1, row h0
        op[HWSZ + WW_] = y1b;   // c=2s+1, row h0+1
        __syncthreads();
    }
}

extern "C" void kernel_launch(void* const* d_in, const int* in_sizes, int n_in,
                              void* d_out, int out_size, void* d_ws, size_t ws_size,
                              hipStream_t stream) {
    const float* x  = (const float*)d_in[0];
    const float* Wq = (const float*)d_in[1];
    const float* bq = (const float*)d_in[2];
    const float* Wk = (const float*)d_in[3];
    const float* bk = (const float*)d_in[4];
    const float* Wv = (const float*)d_in[5];
    const float* bv = (const float*)d_in[6];
    float* out = (float*)d_out;
    float* qkv = (float*)d_ws;   // 3*BCHW*4 = 50.3 MB scratch

    // d_out doubles as scratch for bf16 W (196 KB); fully overwritten by
    // locatt afterwards (stream-ordered), safe under re-poisoning.
    unsigned short* whi = (unsigned short*)d_out;
    unsigned short* wlo = whi + 3*16384;

    prep_w  <<<192, 256, 0, stream>>>(Wq, Wk, Wv, whi, wlo);
    qkv_mfma<<<dim3(256, 3), 256, 0, stream>>>(x, whi, wlo, bq, bk, bv, qkv);
    locatt  <<<256, 512, 0, stream>>>(qkv, out);
}